// Round 2
// baseline (592.897 us; speedup 1.0000x reference)
//
#include <hip/hip_runtime.h>
#include <cstdint>

#define HIDDEN 128
#define BM 64
#define BK 16
#define LDA_S 20    // padded LDS stride for As [64][20]
#define LDB_S 132   // padded LDS stride for Bs [16][132]

// ---------------- CSR build ----------------
// NOTE: harness passes integer inputs as int32 (edge_index: [2, E] int32).

__global__ void k_hist(const int* __restrict__ ei, int E, int* __restrict__ deg) {
    int i = blockIdx.x * blockDim.x + threadIdx.x;
    int stride = gridDim.x * blockDim.x;
    for (int e = i; e < E; e += stride) {
        int d = ei[E + e];   // dst row
        atomicAdd(&deg[d], 1);
    }
}

__global__ void k_scan1(const int* __restrict__ deg, int* __restrict__ rowp,
                        int* __restrict__ bsums, int n) {
    __shared__ int sh[1024];
    int t = threadIdx.x;
    int base = blockIdx.x * 1024;
    int v = (base + t < n) ? deg[base + t] : 0;
    sh[t] = v;
    __syncthreads();
    for (int off = 1; off < 1024; off <<= 1) {
        int x = sh[t];
        int y = (t >= off) ? sh[t - off] : 0;
        __syncthreads();
        sh[t] = x + y;
        __syncthreads();
    }
    if (base + t < n) rowp[base + t + 1] = sh[t];
    if (t == 1023) bsums[blockIdx.x] = sh[1023];
}

__global__ void k_scan2(int* __restrict__ bsums, int nb) {
    if (threadIdx.x == 0 && blockIdx.x == 0) {
        int run = 0;
        for (int b = 0; b < nb; ++b) { int v = bsums[b]; bsums[b] = run; run += v; }
    }
}

__global__ void k_scan3(int* __restrict__ rowp, const int* __restrict__ boffs, int n) {
    int t = threadIdx.x;
    int b = blockIdx.x;
    int base = b * 1024;
    if (base + t < n) rowp[base + t + 1] += boffs[b];
    if (b == 0 && t == 0) rowp[0] = 0;
}

__global__ void k_copy_int(const int* __restrict__ src, int* __restrict__ dst, int n) {
    int i = blockIdx.x * blockDim.x + threadIdx.x;
    if (i < n) dst[i] = src[i];
}

__global__ void k_fill(const int* __restrict__ ei, int E,
                       int* __restrict__ fillpos, int* __restrict__ colx) {
    int i = blockIdx.x * blockDim.x + threadIdx.x;
    int stride = gridDim.x * blockDim.x;
    for (int e = i; e < E; e += stride) {
        int s = ei[e];
        int d = ei[E + e];
        int p = atomicAdd(&fillpos[d], 1);
        colx[p] = s;
    }
}

// ---------------- aggregation: S[n] = (1/max(deg,1)) * sum_{e in CSR[n]} h[col[e]] ----------------

__global__ void k_agg(const float4* __restrict__ h4, const int* __restrict__ rowp,
                      const int* __restrict__ colx, float4* __restrict__ S4, int n) {
    int g = (blockIdx.x * blockDim.x + threadIdx.x) >> 5;   // node index (32 lanes / node)
    int lane = threadIdx.x & 31;
    if (g >= n) return;
    int beg = rowp[g];
    int end = rowp[g + 1];
    float4 acc = make_float4(0.f, 0.f, 0.f, 0.f);
    for (int e = beg; e < end; ++e) {
        int s = colx[e];
        float4 v = h4[(size_t)s * 32 + lane];
        acc.x += v.x; acc.y += v.y; acc.z += v.z; acc.w += v.w;
    }
    int deg = end - beg;
    float inv = 1.0f / (float)(deg > 1 ? deg : 1);
    acc.x *= inv; acc.y *= inv; acc.z *= inv; acc.w *= inv;
    S4[(size_t)g * 32 + lane] = acc;
}

// ---------------- fused GEMM: C = act(A1@W1 + A2@W2 + bias), N = 128 ----------------

__global__ __launch_bounds__(256) void k_gemm(
    const float* __restrict__ A1, const float* __restrict__ W1, int K1,
    const float* __restrict__ A2, const float* __restrict__ W2, int K2,
    const float* __restrict__ bias, float* __restrict__ C, int M, int do_elu)
{
    __shared__ float As[BM * LDA_S];
    __shared__ float Bs[BK * LDB_S];

    int tid = threadIdx.x;
    int tx = tid & 15;         // 0..15 -> cols tx*8..tx*8+7
    int ty = tid >> 4;         // 0..15 -> rows ty*4..ty*4+3
    int row0 = blockIdx.x * BM;

    float acc[4][8];
#pragma unroll
    for (int i = 0; i < 4; ++i)
#pragma unroll
        for (int j = 0; j < 8; ++j) acc[i][j] = 0.f;

    int ldrow = tid >> 2;          // 0..63
    int ldkq = (tid & 3) * 4;      // 0,4,8,12
    int bk = tid >> 4;             // 0..15
    int bn = (tid & 15) * 8;       // 0..120

    for (int part = 0; part < 2; ++part) {
        const float* A = part ? A2 : A1;
        const float* W = part ? W2 : W1;
        int K = part ? K2 : K1;
        if (K == 0 || A == nullptr) continue;

        for (int k0 = 0; k0 < K; k0 += BK) {
            // global loads (issue before barrier)
            float4 av = make_float4(0.f, 0.f, 0.f, 0.f);
            int gr = row0 + ldrow;
            if (gr < M) av = *(const float4*)&A[(size_t)gr * K + k0 + ldkq];
            float4 b0 = *(const float4*)&W[(size_t)(k0 + bk) * HIDDEN + bn];
            float4 b1 = *(const float4*)&W[(size_t)(k0 + bk) * HIDDEN + bn + 4];

            __syncthreads();   // previous tile fully consumed
            *(float4*)&As[ldrow * LDA_S + ldkq] = av;
            *(float4*)&Bs[bk * LDB_S + bn] = b0;
            *(float4*)&Bs[bk * LDB_S + bn + 4] = b1;
            __syncthreads();

#pragma unroll
            for (int k = 0; k < BK; ++k) {
                float a[4], b[8];
#pragma unroll
                for (int i = 0; i < 4; ++i) a[i] = As[(ty * 4 + i) * LDA_S + k];
#pragma unroll
                for (int j = 0; j < 8; ++j) b[j] = Bs[k * LDB_S + tx * 8 + j];
#pragma unroll
                for (int i = 0; i < 4; ++i)
#pragma unroll
                    for (int j = 0; j < 8; ++j) acc[i][j] += a[i] * b[j];
            }
        }
    }

    // epilogue
#pragma unroll
    for (int i = 0; i < 4; ++i) {
        int gr = row0 + ty * 4 + i;
        if (gr < M) {
#pragma unroll
            for (int j = 0; j < 8; ++j) {
                int col = tx * 8 + j;
                float v = acc[i][j] + bias[col];
                if (do_elu) v = (v > 0.f) ? v : expm1f(v);
                C[(size_t)gr * HIDDEN + col] = v;
            }
        }
    }
}

// ---------------- launch ----------------

extern "C" void kernel_launch(void* const* d_in, const int* in_sizes, int n_in,
                              void* d_out, int out_size, void* d_ws, size_t ws_size,
                              hipStream_t stream) {
    const float* x        = (const float*)d_in[0];
    const int* ei         = (const int*)d_in[1];   // int64 in reference -> int32 from harness
    const float* W_in     = (const float*)d_in[2];
    const float* b_in     = (const float*)d_in[3];
    const float* W_self   = (const float*)d_in[4];
    const float* b_self   = (const float*)d_in[5];
    const float* W_nbr    = (const float*)d_in[6];
    float* out = (float*)d_out;

    const int IN_FEAT = 64;
    int N = in_sizes[0] / IN_FEAT;           // 50000
    int E = in_sizes[1] / 2;                 // 800000
    int L = in_sizes[4] / (HIDDEN * HIDDEN); // 3

    char* ws = (char*)d_ws;
    size_t off = 0;
    auto alloc = [&](size_t bytes) -> void* {
        void* p = ws + off;
        off = (off + bytes + 255) & ~(size_t)255;
        return p;
    };

    float* h    = (float*)alloc((size_t)N * HIDDEN * sizeof(float));
    float* S    = (float*)alloc((size_t)N * HIDDEN * sizeof(float));
    int* deg    = (int*)alloc((size_t)N * sizeof(int));
    int* rowp   = (int*)alloc((size_t)(N + 1) * sizeof(int));
    int* fillp  = (int*)alloc((size_t)N * sizeof(int));
    int* colx   = (int*)alloc((size_t)E * sizeof(int));
    int* bsums  = (int*)alloc(256 * sizeof(int));

    // CSR build (graph identical for all layers)
    hipMemsetAsync(deg, 0, (size_t)N * sizeof(int), stream);
    k_hist<<<512, 256, 0, stream>>>(ei, E, deg);
    int nb = (N + 1023) / 1024;
    k_scan1<<<nb, 1024, 0, stream>>>(deg, rowp, bsums, N);
    k_scan2<<<1, 64, 0, stream>>>(bsums, nb);
    k_scan3<<<nb, 1024, 0, stream>>>(rowp, bsums, N);
    k_copy_int<<<(N + 255) / 256, 256, 0, stream>>>(rowp, fillp, N);
    k_fill<<<1024, 256, 0, stream>>>(ei, E, fillp, colx);

    int gblocks = (N + BM - 1) / BM;

    // input projection: h = x @ W_in + b_in   (no activation)
    k_gemm<<<gblocks, 256, 0, stream>>>(x, W_in, IN_FEAT,
                                        nullptr, nullptr, 0,
                                        b_in, h, N, 0);

    for (int l = 0; l < L; ++l) {
        // S = scatter_mean(h[src], dst)
        k_agg<<<(N + 7) / 8, 256, 0, stream>>>((const float4*)h, rowp, colx,
                                               (float4*)S, N);
        const float* Ws = W_self + (size_t)l * HIDDEN * HIDDEN;
        const float* Wn = W_nbr  + (size_t)l * HIDDEN * HIDDEN;
        const float* bs = b_self + (size_t)l * HIDDEN;
        float* dst = (l == L - 1) ? out : h;   // in-place safe: each block reads only its own rows
        k_gemm<<<gblocks, 256, 0, stream>>>(h, Ws, HIDDEN,
                                            S, Wn, HIDDEN,
                                            bs, dst, N, 1);
    }
}

// Round 3
// 577.800 us; speedup vs baseline: 1.0261x; 1.0261x over previous
//
#include <hip/hip_runtime.h>
#include <cstdint>

#define HIDDEN 128
#define BM 64
#define BK 32
#define LDA 68     // As is K-major: As[BK][LDA], rows 0..63 used; 68 keeps 16B align
#define LDB 128    // Bs[BK][128], unpadded (col-group remap avoids conflicts)

// ---------------- CSR build ----------------
// Harness passes integer inputs as int32 (edge_index: [2, E] int32).

__global__ void k_hist(const int* __restrict__ ei, int E, int* __restrict__ deg) {
    int i = blockIdx.x * blockDim.x + threadIdx.x;
    int stride = gridDim.x * blockDim.x;
    for (int e = i; e < E; e += stride) {
        int d = ei[E + e];
        atomicAdd(&deg[d], 1);
    }
}

__global__ void k_scan1(const int* __restrict__ deg, int* __restrict__ rowp,
                        int* __restrict__ bsums, int n) {
    __shared__ int sh[1024];
    int t = threadIdx.x;
    int base = blockIdx.x * 1024;
    int v = (base + t < n) ? deg[base + t] : 0;
    sh[t] = v;
    __syncthreads();
    for (int off = 1; off < 1024; off <<= 1) {
        int x = sh[t];
        int y = (t >= off) ? sh[t - off] : 0;
        __syncthreads();
        sh[t] = x + y;
        __syncthreads();
    }
    if (base + t < n) rowp[base + t + 1] = sh[t];
    if (t == 1023) bsums[blockIdx.x] = sh[1023];
}

__global__ void k_scan2(int* __restrict__ bsums, int nb) {
    if (threadIdx.x == 0 && blockIdx.x == 0) {
        int run = 0;
        for (int b = 0; b < nb; ++b) { int v = bsums[b]; bsums[b] = run; run += v; }
    }
}

__global__ void k_scan3(int* __restrict__ rowp, const int* __restrict__ boffs, int n) {
    int t = threadIdx.x;
    int b = blockIdx.x;
    int base = b * 1024;
    if (base + t < n) rowp[base + t + 1] += boffs[b];
    if (b == 0 && t == 0) rowp[0] = 0;
}

__global__ void k_copy_int(const int* __restrict__ src, int* __restrict__ dst, int n) {
    int i = blockIdx.x * blockDim.x + threadIdx.x;
    if (i < n) dst[i] = src[i];
}

__global__ void k_fill(const int* __restrict__ ei, int E,
                       int* __restrict__ fillpos, int* __restrict__ colx) {
    int i = blockIdx.x * blockDim.x + threadIdx.x;
    int stride = gridDim.x * blockDim.x;
    for (int e = i; e < E; e += stride) {
        int s = ei[e];
        int d = ei[E + e];
        int p = atomicAdd(&fillpos[d], 1);
        colx[p] = s;
    }
}

// ---------------- aggregation: S[n] = mean of h[col[e]] over CSR row n ----------------

__global__ void k_agg(const float4* __restrict__ h4, const int* __restrict__ rowp,
                      const int* __restrict__ colx, float4* __restrict__ S4, int n) {
    int g = (blockIdx.x * blockDim.x + threadIdx.x) >> 5;   // 32 lanes / node
    int lane = threadIdx.x & 31;
    if (g >= n) return;
    int beg = rowp[g];
    int end = rowp[g + 1];
    float4 a0 = make_float4(0.f, 0.f, 0.f, 0.f);
    float4 a1 = a0, a2 = a0, a3 = a0;
    int e = beg;
    for (; e + 3 < end; e += 4) {
        int s0 = colx[e], s1 = colx[e + 1], s2 = colx[e + 2], s3 = colx[e + 3];
        float4 v0 = h4[(size_t)s0 * 32 + lane];
        float4 v1 = h4[(size_t)s1 * 32 + lane];
        float4 v2 = h4[(size_t)s2 * 32 + lane];
        float4 v3 = h4[(size_t)s3 * 32 + lane];
        a0.x += v0.x; a0.y += v0.y; a0.z += v0.z; a0.w += v0.w;
        a1.x += v1.x; a1.y += v1.y; a1.z += v1.z; a1.w += v1.w;
        a2.x += v2.x; a2.y += v2.y; a2.z += v2.z; a2.w += v2.w;
        a3.x += v3.x; a3.y += v3.y; a3.z += v3.z; a3.w += v3.w;
    }
    for (; e < end; ++e) {
        int s = colx[e];
        float4 v = h4[(size_t)s * 32 + lane];
        a0.x += v.x; a0.y += v.y; a0.z += v.z; a0.w += v.w;
    }
    float4 acc;
    acc.x = (a0.x + a1.x) + (a2.x + a3.x);
    acc.y = (a0.y + a1.y) + (a2.y + a3.y);
    acc.z = (a0.z + a1.z) + (a2.z + a3.z);
    acc.w = (a0.w + a1.w) + (a2.w + a3.w);
    int deg = end - beg;
    float inv = 1.0f / (float)(deg > 1 ? deg : 1);
    acc.x *= inv; acc.y *= inv; acc.z *= inv; acc.w *= inv;
    S4[(size_t)g * 32 + lane] = acc;
}

// ---------------- fused GEMM: C = act(A1@W1 + A2@W2 + bias), N = 128 ----------------
// thread tile: 4 rows x 8 cols, cols as two float4 groups 64 apart (kills 4-way
// bank conflicts: lane stride becomes 16B -> 2-way, free). As stored K-major so
// a-fragment is a single ds_read_b128.

__global__ __launch_bounds__(256) void k_gemm(
    const float* __restrict__ A1, const float* __restrict__ W1, int K1,
    const float* __restrict__ A2, const float* __restrict__ W2, int K2,
    const float* __restrict__ bias, float* __restrict__ C, int M, int do_elu)
{
    __shared__ float As[BK * LDA];   // 32*68*4 = 8704 B, K-major [k][row]
    __shared__ float Bs[BK * LDB];   // 32*128*4 = 16384 B, [k][col]

    int tid = threadIdx.x;
    int tx = tid & 15;          // col groups: tx*4 and 64+tx*4
    int ty = tid >> 4;          // rows ty*4 .. ty*4+3
    int row0 = blockIdx.x * BM;

    float acc[4][8];
#pragma unroll
    for (int i = 0; i < 4; ++i)
#pragma unroll
        for (int j = 0; j < 8; ++j) acc[i][j] = 0.f;

    // A staging: 2 quads/thread. quad q: row=q>>3 (0..63), kq=(q&7)*4
    int ar0 = tid >> 3;             // quad 0 row (0..31)  [q = tid]
    int ak0 = (tid & 7) * 4;
    int ar1 = (tid + 256) >> 3;     // quad 1 row (32..63)
    int ak1 = ak0;
    // B staging: 4 quads/thread. quad q = tid + p*256: bk=q>>5 (0..31), bq=(q&31)*4
    int bcol = (tid & 31) * 4;

    for (int part = 0; part < 2; ++part) {
        const float* A = part ? A2 : A1;
        const float* W = part ? W2 : W1;
        int K = part ? K2 : K1;
        if (K == 0 || A == nullptr) continue;

        for (int k0 = 0; k0 < K; k0 += BK) {
            // global loads first (prefetch into regs)
            float4 av0 = make_float4(0.f, 0.f, 0.f, 0.f);
            float4 av1 = av0;
            int gr0 = row0 + ar0, gr1 = row0 + ar1;
            if (gr0 < M) av0 = *(const float4*)&A[(size_t)gr0 * K + k0 + ak0];
            if (gr1 < M) av1 = *(const float4*)&A[(size_t)gr1 * K + k0 + ak1];
            float4 bv[4];
#pragma unroll
            for (int p = 0; p < 4; ++p) {
                int bk = (tid + p * 256) >> 5;
                bv[p] = *(const float4*)&W[(size_t)(k0 + bk) * HIDDEN + bcol];
            }

            __syncthreads();   // previous tile consumed
            // As K-major scatter (scalar writes, amortized over 32 k-steps)
#pragma unroll
            for (int i = 0; i < 4; ++i) As[(ak0 + i) * LDA + ar0] = (&av0.x)[i];
#pragma unroll
            for (int i = 0; i < 4; ++i) As[(ak1 + i) * LDA + ar1] = (&av1.x)[i];
#pragma unroll
            for (int p = 0; p < 4; ++p) {
                int bk = (tid + p * 256) >> 5;
                *(float4*)&Bs[bk * LDB + bcol] = bv[p];
            }
            __syncthreads();

#pragma unroll
            for (int k = 0; k < BK; ++k) {
                float4 a = *(const float4*)&As[k * LDA + ty * 4];
                float4 b0 = *(const float4*)&Bs[k * LDB + tx * 4];
                float4 b1 = *(const float4*)&Bs[k * LDB + 64 + tx * 4];
                const float* ap = &a.x;
                const float* bp0 = &b0.x;
                const float* bp1 = &b1.x;
#pragma unroll
                for (int i = 0; i < 4; ++i) {
#pragma unroll
                    for (int j = 0; j < 4; ++j) {
                        acc[i][j]     += ap[i] * bp0[j];
                        acc[i][j + 4] += ap[i] * bp1[j];
                    }
                }
            }
        }
    }

    // epilogue: two float4 stores per row
#pragma unroll
    for (int i = 0; i < 4; ++i) {
        int gr = row0 + ty * 4 + i;
        if (gr < M) {
            float4 o0, o1;
#pragma unroll
            for (int j = 0; j < 4; ++j) {
                int c0 = tx * 4 + j;
                int c1 = 64 + tx * 4 + j;
                float v0 = acc[i][j] + bias[c0];
                float v1 = acc[i][j + 4] + bias[c1];
                if (do_elu) {
                    v0 = (v0 > 0.f) ? v0 : expm1f(v0);
                    v1 = (v1 > 0.f) ? v1 : expm1f(v1);
                }
                (&o0.x)[j] = v0;
                (&o1.x)[j] = v1;
            }
            *(float4*)&C[(size_t)gr * HIDDEN + tx * 4] = o0;
            *(float4*)&C[(size_t)gr * HIDDEN + 64 + tx * 4] = o1;
        }
    }
}

// ---------------- launch ----------------

extern "C" void kernel_launch(void* const* d_in, const int* in_sizes, int n_in,
                              void* d_out, int out_size, void* d_ws, size_t ws_size,
                              hipStream_t stream) {
    const float* x        = (const float*)d_in[0];
    const int* ei         = (const int*)d_in[1];
    const float* W_in     = (const float*)d_in[2];
    const float* b_in     = (const float*)d_in[3];
    const float* W_self   = (const float*)d_in[4];
    const float* b_self   = (const float*)d_in[5];
    const float* W_nbr    = (const float*)d_in[6];
    float* out = (float*)d_out;

    const int IN_FEAT = 64;
    int N = in_sizes[0] / IN_FEAT;           // 50000
    int E = in_sizes[1] / 2;                 // 800000
    int L = in_sizes[4] / (HIDDEN * HIDDEN); // 3

    char* ws = (char*)d_ws;
    size_t off = 0;
    auto alloc = [&](size_t bytes) -> void* {
        void* p = ws + off;
        off = (off + bytes + 255) & ~(size_t)255;
        return p;
    };

    float* h    = (float*)alloc((size_t)N * HIDDEN * sizeof(float));
    float* S    = (float*)alloc((size_t)N * HIDDEN * sizeof(float));
    int* deg    = (int*)alloc((size_t)N * sizeof(int));
    int* rowp   = (int*)alloc((size_t)(N + 1) * sizeof(int));
    int* fillp  = (int*)alloc((size_t)N * sizeof(int));
    int* colx   = (int*)alloc((size_t)E * sizeof(int));
    int* bsums  = (int*)alloc(256 * sizeof(int));

    // CSR build (graph identical across layers)
    hipMemsetAsync(deg, 0, (size_t)N * sizeof(int), stream);
    k_hist<<<512, 256, 0, stream>>>(ei, E, deg);
    int nb = (N + 1023) / 1024;
    k_scan1<<<nb, 1024, 0, stream>>>(deg, rowp, bsums, N);
    k_scan2<<<1, 64, 0, stream>>>(bsums, nb);
    k_scan3<<<nb, 1024, 0, stream>>>(rowp, bsums, N);
    k_copy_int<<<(N + 255) / 256, 256, 0, stream>>>(rowp, fillp, N);
    k_fill<<<1024, 256, 0, stream>>>(ei, E, fillp, colx);

    int gblocks = (N + BM - 1) / BM;

    // input projection: h = x @ W_in + b_in   (no activation)
    k_gemm<<<gblocks, 256, 0, stream>>>(x, W_in, IN_FEAT,
                                        nullptr, nullptr, 0,
                                        b_in, h, N, 0);

    for (int l = 0; l < L; ++l) {
        k_agg<<<(N + 7) / 8, 256, 0, stream>>>((const float4*)h, rowp, colx,
                                               (float4*)S, N);
        const float* Ws = W_self + (size_t)l * HIDDEN * HIDDEN;
        const float* Wn = W_nbr  + (size_t)l * HIDDEN * HIDDEN;
        const float* bs = b_self + (size_t)l * HIDDEN;
        float* dst = (l == L - 1) ? out : h;   // in-place safe per-block
        k_gemm<<<gblocks, 256, 0, stream>>>(h, Ws, HIDDEN,
                                            S, Wn, HIDDEN,
                                            bs, dst, N, 1);
    }
}

// Round 4
// 486.419 us; speedup vs baseline: 1.2189x; 1.1879x over previous
//
#include <hip/hip_runtime.h>
#include <cstdint>

#define HIDDEN 128
#define BM 64
#define BK 16
#define LDA 68     // As K-major: As[BK][LDA] (cols 0..63 used); 68 keeps alignment, 2-way-only conflicts
#define LDB 128    // Bs[BK][128]; col-group split keeps reads conflict-free

// ---------------- CSR build (edge_index arrives as int32 from harness) ----------------

__global__ void k_hist(const int* __restrict__ ei, int E, int* __restrict__ deg) {
    int i = blockIdx.x * blockDim.x + threadIdx.x;
    int stride = gridDim.x * blockDim.x;
    for (int e = i; e < E; e += stride) {
        int d = ei[E + e];
        atomicAdd(&deg[d], 1);
    }
}

__global__ void k_scan1(const int* __restrict__ deg, int* __restrict__ rowp,
                        int* __restrict__ bsums, int n) {
    __shared__ int sh[1024];
    int t = threadIdx.x;
    int base = blockIdx.x * 1024;
    int v = (base + t < n) ? deg[base + t] : 0;
    sh[t] = v;
    __syncthreads();
    for (int off = 1; off < 1024; off <<= 1) {
        int x = sh[t];
        int y = (t >= off) ? sh[t - off] : 0;
        __syncthreads();
        sh[t] = x + y;
        __syncthreads();
    }
    if (base + t < n) rowp[base + t + 1] = sh[t];
    if (t == 1023) bsums[blockIdx.x] = sh[1023];
}

__global__ void k_scan2(int* __restrict__ bsums, int nb) {
    if (threadIdx.x == 0 && blockIdx.x == 0) {
        int run = 0;
        for (int b = 0; b < nb; ++b) { int v = bsums[b]; bsums[b] = run; run += v; }
    }
}

__global__ void k_scan3(int* __restrict__ rowp, const int* __restrict__ boffs, int n) {
    int t = threadIdx.x;
    int b = blockIdx.x;
    int base = b * 1024;
    if (base + t < n) rowp[base + t + 1] += boffs[b];
    if (b == 0 && t == 0) rowp[0] = 0;
}

__global__ void k_copy_int(const int* __restrict__ src, int* __restrict__ dst, int n) {
    int i = blockIdx.x * blockDim.x + threadIdx.x;
    if (i < n) dst[i] = src[i];
}

__global__ void k_fill(const int* __restrict__ ei, int E,
                       int* __restrict__ fillpos, int* __restrict__ colx) {
    int i = blockIdx.x * blockDim.x + threadIdx.x;
    int stride = gridDim.x * blockDim.x;
    for (int e = i; e < E; e += stride) {
        int s = ei[e];
        int d = ei[E + e];
        int p = atomicAdd(&fillpos[d], 1);
        colx[p] = s;
    }
}

// ---------------- aggregation over bf16 h: S[n] = mean of hb[col[e]] (fp32 accumulate) ----------------

__device__ __forceinline__ float bf2f(unsigned short u) {
    union { unsigned int i; float f; } c;
    c.i = ((unsigned int)u) << 16;
    return c.f;
}

__global__ void k_agg(const ushort4* __restrict__ hb4, const int* __restrict__ rowp,
                      const int* __restrict__ colx, float4* __restrict__ S4, int n) {
    int g = (blockIdx.x * blockDim.x + threadIdx.x) >> 5;   // 32 lanes / node, lane covers 4 cols
    int lane = threadIdx.x & 31;
    if (g >= n) return;
    int beg = rowp[g];
    int end = rowp[g + 1];
    float4 a0 = make_float4(0.f, 0.f, 0.f, 0.f);
    float4 a1 = a0, a2 = a0, a3 = a0;
    int e = beg;
    for (; e + 3 < end; e += 4) {
        int s0 = colx[e], s1 = colx[e + 1], s2 = colx[e + 2], s3 = colx[e + 3];
        ushort4 v0 = hb4[(size_t)s0 * 32 + lane];
        ushort4 v1 = hb4[(size_t)s1 * 32 + lane];
        ushort4 v2 = hb4[(size_t)s2 * 32 + lane];
        ushort4 v3 = hb4[(size_t)s3 * 32 + lane];
        a0.x += bf2f(v0.x); a0.y += bf2f(v0.y); a0.z += bf2f(v0.z); a0.w += bf2f(v0.w);
        a1.x += bf2f(v1.x); a1.y += bf2f(v1.y); a1.z += bf2f(v1.z); a1.w += bf2f(v1.w);
        a2.x += bf2f(v2.x); a2.y += bf2f(v2.y); a2.z += bf2f(v2.z); a2.w += bf2f(v2.w);
        a3.x += bf2f(v3.x); a3.y += bf2f(v3.y); a3.z += bf2f(v3.z); a3.w += bf2f(v3.w);
    }
    for (; e < end; ++e) {
        int s = colx[e];
        ushort4 v = hb4[(size_t)s * 32 + lane];
        a0.x += bf2f(v.x); a0.y += bf2f(v.y); a0.z += bf2f(v.z); a0.w += bf2f(v.w);
    }
    float4 acc;
    acc.x = (a0.x + a1.x) + (a2.x + a3.x);
    acc.y = (a0.y + a1.y) + (a2.y + a3.y);
    acc.z = (a0.z + a1.z) + (a2.z + a3.z);
    acc.w = (a0.w + a1.w) + (a2.w + a3.w);
    int deg = end - beg;
    float inv = 1.0f / (float)(deg > 1 ? deg : 1);
    acc.x *= inv; acc.y *= inv; acc.z *= inv; acc.w *= inv;
    S4[(size_t)g * 32 + lane] = acc;
}

// ---------------- fused GEMM: C = act(A1@W1 + A2@W2 + bias); optional bf16 copy of C ----------------
// BK=16 keeps staged registers at 3 float4/thread (no spill). As is K-major so the
// a-fragment is one ds_read_b128; b-fragments are two float4 groups 64 cols apart
// (lane stride 16B -> 2-way bank aliasing only, which is free).

__device__ __forceinline__ unsigned short f2bf(float f) {
    unsigned int u = __float_as_uint(f);
    unsigned int r = (u + 0x7fffu + ((u >> 16) & 1u)) >> 16;   // RNE
    return (unsigned short)r;
}

__global__ __launch_bounds__(256) void k_gemm(
    const float* __restrict__ A1, const float* __restrict__ W1, int K1,
    const float* __restrict__ A2, const float* __restrict__ W2, int K2,
    const float* __restrict__ bias, float* __restrict__ C,
    unsigned short* __restrict__ hb, int M, int do_elu)
{
    __shared__ float As[BK * LDA];   // 16*68*4 = 4352 B, K-major [k][row]
    __shared__ float Bs[BK * LDB];   // 16*128*4 = 8192 B, [k][col]

    int tid = threadIdx.x;
    int tx = tid & 15;          // col groups: tx*4 and 64+tx*4
    int ty = tid >> 4;          // rows ty*4 .. ty*4+3
    int row0 = blockIdx.x * BM;

    float acc[4][8];
#pragma unroll
    for (int i = 0; i < 4; ++i)
#pragma unroll
        for (int j = 0; j < 8; ++j) acc[i][j] = 0.f;

    // A staging: 1 quad/thread: row = tid>>2 (0..63), k = (tid&3)*4
    int ar = tid >> 2;
    int ak = (tid & 3) * 4;
    // B staging: 2 quads/thread: q = tid + p*256 -> bk = q>>5 (0..15), bcol = (q&31)*4
    int bcol = (tid & 31) * 4;
    int bk0 = tid >> 5;          // p = 0: 0..7
    int bk1 = bk0 + 8;           // p = 1: 8..15

    for (int part = 0; part < 2; ++part) {
        const float* A = part ? A2 : A1;
        const float* W = part ? W2 : W1;
        int K = part ? K2 : K1;
        if (K == 0 || A == nullptr) continue;

        for (int k0 = 0; k0 < K; k0 += BK) {
            // prefetch to registers (3 float4 live across the barrier)
            float4 av = make_float4(0.f, 0.f, 0.f, 0.f);
            int gr = row0 + ar;
            if (gr < M) av = *(const float4*)&A[(size_t)gr * K + k0 + ak];
            float4 bv0 = *(const float4*)&W[(size_t)(k0 + bk0) * HIDDEN + bcol];
            float4 bv1 = *(const float4*)&W[(size_t)(k0 + bk1) * HIDDEN + bcol];

            __syncthreads();   // previous tile consumed
#pragma unroll
            for (int i = 0; i < 4; ++i) As[(ak + i) * LDA + ar] = (&av.x)[i];
            *(float4*)&Bs[bk0 * LDB + bcol] = bv0;
            *(float4*)&Bs[bk1 * LDB + bcol] = bv1;
            __syncthreads();

#pragma unroll
            for (int k = 0; k < BK; ++k) {
                float4 a  = *(const float4*)&As[k * LDA + ty * 4];
                float4 b0 = *(const float4*)&Bs[k * LDB + tx * 4];
                float4 b1 = *(const float4*)&Bs[k * LDB + 64 + tx * 4];
                const float* ap = &a.x;
                const float* bp0 = &b0.x;
                const float* bp1 = &b1.x;
#pragma unroll
                for (int i = 0; i < 4; ++i) {
#pragma unroll
                    for (int j = 0; j < 4; ++j) {
                        acc[i][j]     += ap[i] * bp0[j];
                        acc[i][j + 4] += ap[i] * bp1[j];
                    }
                }
            }
        }
    }

    // epilogue: bias + optional ELU, fp32 store, optional bf16 mirror
#pragma unroll
    for (int i = 0; i < 4; ++i) {
        int gr = row0 + ty * 4 + i;
        if (gr < M) {
            float4 o0, o1;
#pragma unroll
            for (int j = 0; j < 4; ++j) {
                float v0 = acc[i][j]     + bias[tx * 4 + j];
                float v1 = acc[i][j + 4] + bias[64 + tx * 4 + j];
                if (do_elu) {
                    v0 = (v0 > 0.f) ? v0 : expm1f(v0);
                    v1 = (v1 > 0.f) ? v1 : expm1f(v1);
                }
                (&o0.x)[j] = v0;
                (&o1.x)[j] = v1;
            }
            *(float4*)&C[(size_t)gr * HIDDEN + tx * 4] = o0;
            *(float4*)&C[(size_t)gr * HIDDEN + 64 + tx * 4] = o1;
            if (hb) {
                ushort4 p0, p1;
                p0.x = f2bf(o0.x); p0.y = f2bf(o0.y); p0.z = f2bf(o0.z); p0.w = f2bf(o0.w);
                p1.x = f2bf(o1.x); p1.y = f2bf(o1.y); p1.z = f2bf(o1.z); p1.w = f2bf(o1.w);
                *(ushort4*)&hb[(size_t)gr * HIDDEN + tx * 4] = p0;
                *(ushort4*)&hb[(size_t)gr * HIDDEN + 64 + tx * 4] = p1;
            }
        }
    }
}

// ---------------- launch ----------------

extern "C" void kernel_launch(void* const* d_in, const int* in_sizes, int n_in,
                              void* d_out, int out_size, void* d_ws, size_t ws_size,
                              hipStream_t stream) {
    const float* x        = (const float*)d_in[0];
    const int* ei         = (const int*)d_in[1];
    const float* W_in     = (const float*)d_in[2];
    const float* b_in     = (const float*)d_in[3];
    const float* W_self   = (const float*)d_in[4];
    const float* b_self   = (const float*)d_in[5];
    const float* W_nbr    = (const float*)d_in[6];
    float* out = (float*)d_out;

    const int IN_FEAT = 64;
    int N = in_sizes[0] / IN_FEAT;           // 50000
    int E = in_sizes[1] / 2;                 // 800000
    int L = in_sizes[4] / (HIDDEN * HIDDEN); // 3

    char* ws = (char*)d_ws;
    size_t off = 0;
    auto alloc = [&](size_t bytes) -> void* {
        void* p = ws + off;
        off = (off + bytes + 255) & ~(size_t)255;
        return p;
    };

    float* h            = (float*)alloc((size_t)N * HIDDEN * sizeof(float));
    float* S            = (float*)alloc((size_t)N * HIDDEN * sizeof(float));
    unsigned short* hb  = (unsigned short*)alloc((size_t)N * HIDDEN * sizeof(unsigned short));
    int* deg    = (int*)alloc((size_t)N * sizeof(int));
    int* rowp   = (int*)alloc((size_t)(N + 1) * sizeof(int));
    int* fillp  = (int*)alloc((size_t)N * sizeof(int));
    int* colx   = (int*)alloc((size_t)E * sizeof(int));
    int* bsums  = (int*)alloc(256 * sizeof(int));

    // CSR build (graph identical across layers)
    hipMemsetAsync(deg, 0, (size_t)N * sizeof(int), stream);
    k_hist<<<512, 256, 0, stream>>>(ei, E, deg);
    int nb = (N + 1023) / 1024;
    k_scan1<<<nb, 1024, 0, stream>>>(deg, rowp, bsums, N);
    k_scan2<<<1, 64, 0, stream>>>(bsums, nb);
    k_scan3<<<nb, 1024, 0, stream>>>(rowp, bsums, N);
    k_copy_int<<<(N + 255) / 256, 256, 0, stream>>>(rowp, fillp, N);
    k_fill<<<1024, 256, 0, stream>>>(ei, E, fillp, colx);

    int gblocks = (N + BM - 1) / BM;

    // input projection: h = x @ W_in + b_in (no activation); emit bf16 mirror for layer-0 agg
    k_gemm<<<gblocks, 256, 0, stream>>>(x, W_in, IN_FEAT,
                                        nullptr, nullptr, 0,
                                        b_in, h, hb, N, 0);

    for (int l = 0; l < L; ++l) {
        k_agg<<<(N + 7) / 8, 256, 0, stream>>>((const ushort4*)hb, rowp, colx,
                                               (float4*)S, N);
        const float* Ws = W_self + (size_t)l * HIDDEN * HIDDEN;
        const float* Wn = W_nbr  + (size_t)l * HIDDEN * HIDDEN;
        const float* bs = b_self + (size_t)l * HIDDEN;
        bool last = (l == L - 1);
        float* dst = last ? out : h;                       // in-place safe per-block
        unsigned short* hbo = last ? nullptr : hb;         // final h not aggregated again
        k_gemm<<<gblocks, 256, 0, stream>>>(h, Ws, HIDDEN,
                                            S, Wn, HIDDEN,
                                            bs, dst, hbo, N, 1);
    }
}